// Round 6
// baseline (124.763 us; speedup 1.0000x reference)
//
#include <hip/hip_runtime.h>

#define PN 131072
#define PH 1024
#define WPB 8               // waves per block (grid_eval)
#define HPW (PH / WPB)      // 128 h per wave
#define G 128               // interpolation grid side
#define GPTS (G * G)

// ---- workspace layout (float offsets) ----
// [0..8191]   pk (1024 * 8 floats)
// [8192]      sw2 (sum of w2)
// [8200..8203] bounds as ordered-uint keys: min0, max0, min1, max1
// [8448..]    grid float4[G*G]  (16B aligned: 8448*4 % 16 == 0)

static __device__ __forceinline__ unsigned fkey(float f) {
    unsigned u = __float_as_uint(f);
    return (u & 0x80000000u) ? ~u : (u | 0x80000000u);
}
static __device__ __forceinline__ float funkey(unsigned k) {
    unsigned u = (k & 0x80000000u) ? (k ^ 0x80000000u) : ~k;
    return __uint_as_float(u);
}
// returns {lo0, step0, lo1, step1}
static __device__ __forceinline__ float4 grid_map(const unsigned* __restrict__ bnd) {
    const float mn0 = funkey(bnd[0]), mx0 = funkey(bnd[1]);
    const float mn1 = funkey(bnd[2]), mx1 = funkey(bnd[3]);
    const float pad0 = 1e-4f * (mx0 - mn0) + 1e-6f;
    const float pad1 = 1e-4f * (mx1 - mn1) + 1e-6f;
    const float lo0 = mn0 - pad0, hi0 = mx0 + pad0;
    const float lo1 = mn1 - pad1, hi1 = mx1 + pad1;
    return make_float4(lo0, (hi0 - lo0) * (1.0f / (G - 1)),
                       lo1, (hi1 - lo1) * (1.0f / (G - 1)));
}

// pk[h] = {w10s, w11s, b1s, co, c1, c2, c3, c4}; also inits bounds slots.
__global__ __launch_bounds__(256) void prep_kernel(const float* __restrict__ W1,
                                                   const float* __restrict__ b1,
                                                   const float* __restrict__ w2,
                                                   float* __restrict__ pk,
                                                   float* __restrict__ sw2out,
                                                   unsigned* __restrict__ bnd) {
    const float SC = 2.8853900817779268f;   // 2*log2(e)
    const int t = threadIdx.x;
    if (t == 0) {
        bnd[0] = 0xFFFFFFFFu; bnd[1] = 0u;   // min0, max0
        bnd[2] = 0xFFFFFFFFu; bnd[3] = 0u;   // min1, max1
    }
    float wsum = 0.0f;
    #pragma unroll
    for (int k = 0; k < 4; ++k) {
        const int h = t + k * 256;
        const float w10 = W1[2 * h], w11 = W1[2 * h + 1], w2h = w2[h];
        float* q = pk + (size_t)h * 8;
        q[0] = w10 * SC;
        q[1] = w11 * SC;
        q[2] = b1[h] * SC;
        q[3] = -2.0f * w2h;
        q[4] = 4.0f * w10 * w2h;
        q[5] = 4.0f * w11 * w2h;
        q[6] = 4.0f * w11 * w11 * w2h;
        q[7] = -8.0f * w11 * w11 * w2h;
        wsum += w2h;
    }
    __shared__ float red[4];
    #pragma unroll
    for (int m = 32; m >= 1; m >>= 1) wsum += __shfl_xor(wsum, m, 64);
    const int wv = t >> 6, ln = t & 63;
    if (ln == 0) red[wv] = wsum;
    __syncthreads();
    if (t == 0) sw2out[0] = red[0] + red[1] + red[2] + red[3];
}

__global__ __launch_bounds__(256) void bounds_kernel(const float2* __restrict__ x2,
                                                     unsigned* __restrict__ bnd) {
    const int i = blockIdx.x * 256 + threadIdx.x;
    const float2 v = x2[i];
    unsigned k0 = fkey(v.x), k1 = fkey(v.y);
    unsigned mn0 = k0, mx0 = k0, mn1 = k1, mx1 = k1;
    #pragma unroll
    for (int m = 32; m >= 1; m >>= 1) {
        mn0 = min(mn0, (unsigned)__shfl_xor((int)mn0, m, 64));
        mx0 = max(mx0, (unsigned)__shfl_xor((int)mx0, m, 64));
        mn1 = min(mn1, (unsigned)__shfl_xor((int)mn1, m, 64));
        mx1 = max(mx1, (unsigned)__shfl_xor((int)mx1, m, 64));
    }
    if ((threadIdx.x & 63) == 0) {
        atomicMin(&bnd[0], mn0);
        atomicMax(&bnd[1], mx0);
        atomicMin(&bnd[2], mn1);
        atomicMax(&bnd[3], mx1);
    }
}

// Evaluate (f, df_dt, df_dx, df_dxdx) on the G x G grid. R5 engine, 64 pts/block.
__global__ __launch_bounds__(512, 8) void grid_eval_kernel(const float4* __restrict__ pk4,
                                                           const float* __restrict__ sw2p,
                                                           const float* __restrict__ b2p,
                                                           const unsigned* __restrict__ bnd,
                                                           float4* __restrict__ gridout) {
    const int lane = threadIdx.x & 63;
    const int wv   = threadIdx.x >> 6;
    const int wvu  = __builtin_amdgcn_readfirstlane(wv);
    const int idx  = blockIdx.x * 64 + lane;           // grid point index
    const int ix   = idx & (G - 1);
    const int iy   = idx >> 7;

    const float4 mp = grid_map(bnd);
    const float x0 = __builtin_fmaf((float)ix, mp.y, mp.x);
    const float x1 = __builtin_fmaf((float)iy, mp.w, mp.z);

    const float4* __restrict__ pw = pk4 + (size_t)wvu * (2 * HPW);

    float a_r = 0.f, a_u1 = 0.f, a_u2 = 0.f, a_u3 = 0.f, a_u4 = 0.f;

    #pragma unroll 4
    for (int hp = 0; hp < HPW / 2; ++hp) {
        const float4 A0 = pw[4 * hp + 0];
        const float4 A1 = pw[4 * hp + 1];
        const float4 B0 = pw[4 * hp + 2];
        const float4 B1 = pw[4 * hp + 3];

        float zsa = __builtin_fmaf(x0, A0.x, __builtin_fmaf(x1, A0.y, A0.z));
        float zsb = __builtin_fmaf(x0, B0.x, __builtin_fmaf(x1, B0.y, B0.z));
        zsa = fminf(zsa, 40.0f);
        zsb = fminf(zsb, 40.0f);
        const float ea = __builtin_amdgcn_exp2f(zsa);
        const float eb = __builtin_amdgcn_exp2f(zsb);
        const float da = ea + 1.0f;
        const float db = eb + 1.0f;
        const float rab = __builtin_amdgcn_rcpf(da * db);
        const float ra = rab * db;
        const float rb = rab * da;
        const float ua = __builtin_fmaf(-ra, ra, ra);
        const float ub = __builtin_fmaf(-rb, rb, rb);
        const float rua = ra * ua;
        const float rub = rb * ub;

        a_r  = __builtin_fmaf(ra,  A0.w, a_r);
        a_r  = __builtin_fmaf(rb,  B0.w, a_r);
        a_u1 = __builtin_fmaf(ua,  A1.x, a_u1);
        a_u1 = __builtin_fmaf(ub,  B1.x, a_u1);
        a_u2 = __builtin_fmaf(ua,  A1.y, a_u2);
        a_u2 = __builtin_fmaf(ub,  B1.y, a_u2);
        a_u3 = __builtin_fmaf(ua,  A1.z, a_u3);
        a_u3 = __builtin_fmaf(ub,  B1.z, a_u3);
        a_u4 = __builtin_fmaf(rua, A1.w, a_u4);
        a_u4 = __builtin_fmaf(rub, B1.w, a_u4);
    }

    const float aD = a_u3 + a_u4;

    __shared__ float4 red[WPB][64];
    if (wv != 0) {
        red[wv][lane] = make_float4(a_r, a_u1, a_u2, aD);
    }
    __syncthreads();
    if (wv == 0) {
        float s_r = a_r, s_u1 = a_u1, s_u2 = a_u2, sD = aD;
        #pragma unroll
        for (int w = 1; w < WPB; ++w) {
            const float4 o = red[w][lane];
            s_r += o.x; s_u1 += o.y; s_u2 += o.z; sD += o.w;
        }
        const float f    = sw2p[0] + b2p[0] + s_r;   // sum t*w2 + b2
        const float ft   = s_u1;                     // df_dt
        const float fx   = s_u2;                     // df_dx
        const float fxx  = -2.0f * sD;               // df_dxdx
        gridout[idx] = make_float4(f, ft, fx, fxx);
    }
}

// Catmull-Rom weights for t in [0,1)
static __device__ __forceinline__ void cr_w(float t, float w[4]) {
    w[0] = t * (-0.5f + t * (1.0f - 0.5f * t));
    w[1] = 1.0f + t * t * (-2.5f + 1.5f * t);
    w[2] = t * (0.5f + t * (2.0f - 1.5f * t));
    w[3] = t * t * (-0.5f + 0.5f * t);
}

__global__ __launch_bounds__(256) void interp_kernel(const float2* __restrict__ x2,
                                                     const unsigned* __restrict__ bnd,
                                                     const float4* __restrict__ grid,
                                                     float* __restrict__ out) {
    const int i = blockIdx.x * 256 + threadIdx.x;
    const float2 xv = x2[i];
    const float4 mp = grid_map(bnd);
    const float inv0 = __builtin_amdgcn_rcpf(mp.y);
    const float inv1 = __builtin_amdgcn_rcpf(mp.w);

    float u = (xv.x - mp.x) * inv0;
    float v = (xv.y - mp.z) * inv1;
    u = fminf(fmaxf(u, 0.0f), (float)(G - 1) - 1e-3f);
    v = fminf(fmaxf(v, 0.0f), (float)(G - 1) - 1e-3f);
    int iu = (int)u;  iu = iu > G - 2 ? G - 2 : iu;
    int iv = (int)v;  iv = iv > G - 2 ? G - 2 : iv;
    const float fu = u - (float)iu;
    const float fv = v - (float)iv;

    float wu[4], wv_[4];
    cr_w(fu, wu);
    cr_w(fv, wv_);

    const int ju0 = iu - 1 < 0 ? 0 : iu - 1;
    const int ju1 = iu;
    const int ju2 = iu + 1;
    const int ju3 = iu + 2 > G - 1 ? G - 1 : iu + 2;
    const int jv0 = iv - 1 < 0 ? 0 : iv - 1;
    const int jv3 = iv + 2 > G - 1 ? G - 1 : iv + 2;
    const int rows[4] = { jv0 * G, iv * G, (iv + 1) * G, jv3 * G };

    float af = 0.f, at = 0.f, ax = 0.f, axx = 0.f;
    #pragma unroll
    for (int r = 0; r < 4; ++r) {
        const int base = rows[r];
        const float4 g0 = grid[base + ju0];
        const float4 g1 = grid[base + ju1];
        const float4 g2 = grid[base + ju2];
        const float4 g3 = grid[base + ju3];
        const float rf  = wu[0] * g0.x + wu[1] * g1.x + wu[2] * g2.x + wu[3] * g3.x;
        const float rt  = wu[0] * g0.y + wu[1] * g1.y + wu[2] * g2.y + wu[3] * g3.y;
        const float rx  = wu[0] * g0.z + wu[1] * g1.z + wu[2] * g2.z + wu[3] * g3.z;
        const float rxx = wu[0] * g0.w + wu[1] * g1.w + wu[2] * g2.w + wu[3] * g3.w;
        af  = __builtin_fmaf(wv_[r], rf,  af);
        at  = __builtin_fmaf(wv_[r], rt,  at);
        ax  = __builtin_fmaf(wv_[r], rx,  ax);
        axx = __builtin_fmaf(wv_[r], rxx, axx);
    }

    const float x1 = xv.y;
    const float pde = __builtin_fmaf(0.5f * x1, x1, at)
                    + 0.5f * axx
                    + 0.5f * x1 * ax
                    - 0.069444444444444445f * ax * ax;
    out[i] = af;
    out[PN + i] = pde;
}

extern "C" void kernel_launch(void* const* d_in, const int* in_sizes, int n_in,
                              void* d_out, int out_size, void* d_ws, size_t ws_size,
                              hipStream_t stream) {
    const float* x  = (const float*)d_in[0];
    const float* W1 = (const float*)d_in[1];
    const float* b1 = (const float*)d_in[2];
    const float* w2 = (const float*)d_in[3];
    const float* b2 = (const float*)d_in[4];
    float* out = (float*)d_out;

    float* pk      = (float*)d_ws;                    // 8192 floats
    float* sw2     = pk + 8192;
    unsigned* bnd  = (unsigned*)(pk + 8200);          // 4 uints
    float4* grid   = (float4*)(pk + 8448);            // G*G float4 = 256 KiB

    const float2* x2 = (const float2*)x;

    prep_kernel<<<1, 256, 0, stream>>>(W1, b1, w2, pk, sw2, bnd);
    bounds_kernel<<<PN / 256, 256, 0, stream>>>(x2, bnd);
    grid_eval_kernel<<<GPTS / 64, 512, 0, stream>>>((const float4*)pk, sw2, b2, bnd, grid);
    interp_kernel<<<PN / 256, 256, 0, stream>>>(x2, bnd, grid, out);
}

// Round 7
// 34.553 us; speedup vs baseline: 3.6108x; 3.6108x over previous
//
#include <hip/hip_runtime.h>

#define PN 131072
#define PH 1024
#define WPB 8               // waves per block (grid_eval)
#define HPW (PH / WPB)      // 128 h per wave
#define G 128               // interpolation grid side
#define GPTS (G * G)
#define NB1 128             // bounds stage-1 blocks

// ---- workspace layout (float offsets) ----
// [0..8191]    pk (1024 * 8 floats)
// [8192]       sw2 (sum of w2)
// [8200..8203] bnd: ordered-uint keys min0, max0, min1, max1
// [8208..8719] partials: uint4[NB1]
// [8960..]     grid float4[G*G]  (16B aligned)

static __device__ __forceinline__ unsigned fkey(float f) {
    unsigned u = __float_as_uint(f);
    return (u & 0x80000000u) ? ~u : (u | 0x80000000u);
}
static __device__ __forceinline__ float funkey(unsigned k) {
    unsigned u = (k & 0x80000000u) ? (k ^ 0x80000000u) : ~k;
    return __uint_as_float(u);
}
// returns {lo0, step0, lo1, step1}
static __device__ __forceinline__ float4 grid_map(const unsigned* __restrict__ bnd) {
    const float mn0 = funkey(bnd[0]), mx0 = funkey(bnd[1]);
    const float mn1 = funkey(bnd[2]), mx1 = funkey(bnd[3]);
    const float pad0 = 1e-4f * (mx0 - mn0) + 1e-6f;
    const float pad1 = 1e-4f * (mx1 - mn1) + 1e-6f;
    const float lo0 = mn0 - pad0, hi0 = mx0 + pad0;
    const float lo1 = mn1 - pad1, hi1 = mx1 + pad1;
    return make_float4(lo0, (hi0 - lo0) * (1.0f / (G - 1)),
                       lo1, (hi1 - lo1) * (1.0f / (G - 1)));
}

__global__ __launch_bounds__(256) void prep_kernel(const float* __restrict__ W1,
                                                   const float* __restrict__ b1,
                                                   const float* __restrict__ w2,
                                                   float* __restrict__ pk,
                                                   float* __restrict__ sw2out) {
    const float SC = 2.8853900817779268f;   // 2*log2(e)
    const int t = threadIdx.x;
    float wsum = 0.0f;
    #pragma unroll
    for (int k = 0; k < 4; ++k) {
        const int h = t + k * 256;
        const float w10 = W1[2 * h], w11 = W1[2 * h + 1], w2h = w2[h];
        float* q = pk + (size_t)h * 8;
        q[0] = w10 * SC;
        q[1] = w11 * SC;
        q[2] = b1[h] * SC;
        q[3] = -2.0f * w2h;
        q[4] = 4.0f * w10 * w2h;
        q[5] = 4.0f * w11 * w2h;
        q[6] = 4.0f * w11 * w11 * w2h;
        q[7] = -8.0f * w11 * w11 * w2h;
        wsum += w2h;
    }
    __shared__ float red[4];
    #pragma unroll
    for (int m = 32; m >= 1; m >>= 1) wsum += __shfl_xor(wsum, m, 64);
    const int wv = t >> 6, ln = t & 63;
    if (ln == 0) red[wv] = wsum;
    __syncthreads();
    if (t == 0) sw2out[0] = red[0] + red[1] + red[2] + red[3];
}

// Stage 1: per-block min/max partials, no atomics.
__global__ __launch_bounds__(256) void bounds1_kernel(const float4* __restrict__ x4,
                                                      uint4* __restrict__ part) {
    const int tid = blockIdx.x * 256 + threadIdx.x;
    unsigned mn0 = 0xFFFFFFFFu, mx0 = 0u, mn1 = 0xFFFFFFFFu, mx1 = 0u;
    // 65536 float4 total; NB1*256 = 32768 threads -> 2 each.
    #pragma unroll
    for (int k = 0; k < 2; ++k) {
        const float4 v = x4[tid + k * (NB1 * 256)];
        const unsigned ka0 = fkey(v.x), ka1 = fkey(v.y);
        const unsigned kb0 = fkey(v.z), kb1 = fkey(v.w);
        mn0 = min(mn0, min(ka0, kb0));
        mx0 = max(mx0, max(ka0, kb0));
        mn1 = min(mn1, min(ka1, kb1));
        mx1 = max(mx1, max(ka1, kb1));
    }
    #pragma unroll
    for (int m = 32; m >= 1; m >>= 1) {
        mn0 = min(mn0, (unsigned)__shfl_xor((int)mn0, m, 64));
        mx0 = max(mx0, (unsigned)__shfl_xor((int)mx0, m, 64));
        mn1 = min(mn1, (unsigned)__shfl_xor((int)mn1, m, 64));
        mx1 = max(mx1, (unsigned)__shfl_xor((int)mx1, m, 64));
    }
    __shared__ uint4 red[4];
    const int wv = threadIdx.x >> 6;
    if ((threadIdx.x & 63) == 0) red[wv] = make_uint4(mn0, mx0, mn1, mx1);
    __syncthreads();
    if (threadIdx.x == 0) {
        uint4 a = red[0];
        #pragma unroll
        for (int w = 1; w < 4; ++w) {
            const uint4 o = red[w];
            a.x = min(a.x, o.x); a.y = max(a.y, o.y);
            a.z = min(a.z, o.z); a.w = max(a.w, o.w);
        }
        part[blockIdx.x] = a;
    }
}

// Stage 2: one wave reduces NB1 partials.
__global__ __launch_bounds__(64) void bounds2_kernel(const uint4* __restrict__ part,
                                                     unsigned* __restrict__ bnd) {
    const int ln = threadIdx.x;
    uint4 a = part[ln];
    const uint4 b = part[ln + 64];
    a.x = min(a.x, b.x); a.y = max(a.y, b.y);
    a.z = min(a.z, b.z); a.w = max(a.w, b.w);
    #pragma unroll
    for (int m = 32; m >= 1; m >>= 1) {
        a.x = min(a.x, (unsigned)__shfl_xor((int)a.x, m, 64));
        a.y = max(a.y, (unsigned)__shfl_xor((int)a.y, m, 64));
        a.z = min(a.z, (unsigned)__shfl_xor((int)a.z, m, 64));
        a.w = max(a.w, (unsigned)__shfl_xor((int)a.w, m, 64));
    }
    if (ln == 0) {
        bnd[0] = a.x; bnd[1] = a.y; bnd[2] = a.z; bnd[3] = a.w;
    }
}

// Evaluate (f, df_dt, df_dx, df_dxdx) on the G x G grid.
__global__ __launch_bounds__(512, 8) void grid_eval_kernel(const float4* __restrict__ pk4,
                                                           const float* __restrict__ sw2p,
                                                           const float* __restrict__ b2p,
                                                           const unsigned* __restrict__ bnd,
                                                           float4* __restrict__ gridout) {
    const int lane = threadIdx.x & 63;
    const int wv   = threadIdx.x >> 6;
    const int wvu  = __builtin_amdgcn_readfirstlane(wv);
    const int idx  = blockIdx.x * 64 + lane;           // grid point index
    const int ix   = idx & (G - 1);
    const int iy   = idx >> 7;

    const float4 mp = grid_map(bnd);
    const float x0 = __builtin_fmaf((float)ix, mp.y, mp.x);
    const float x1 = __builtin_fmaf((float)iy, mp.w, mp.z);

    const float4* __restrict__ pw = pk4 + (size_t)wvu * (2 * HPW);

    float a_r = 0.f, a_u1 = 0.f, a_u2 = 0.f, a_u3 = 0.f, a_u4 = 0.f;

    #pragma unroll 4
    for (int hp = 0; hp < HPW / 2; ++hp) {
        const float4 A0 = pw[4 * hp + 0];
        const float4 A1 = pw[4 * hp + 1];
        const float4 B0 = pw[4 * hp + 2];
        const float4 B1 = pw[4 * hp + 3];

        float zsa = __builtin_fmaf(x0, A0.x, __builtin_fmaf(x1, A0.y, A0.z));
        float zsb = __builtin_fmaf(x0, B0.x, __builtin_fmaf(x1, B0.y, B0.z));
        zsa = fminf(zsa, 40.0f);
        zsb = fminf(zsb, 40.0f);
        const float ea = __builtin_amdgcn_exp2f(zsa);
        const float eb = __builtin_amdgcn_exp2f(zsb);
        const float da = ea + 1.0f;
        const float db = eb + 1.0f;
        const float rab = __builtin_amdgcn_rcpf(da * db);
        const float ra = rab * db;
        const float rb = rab * da;
        const float ua = __builtin_fmaf(-ra, ra, ra);
        const float ub = __builtin_fmaf(-rb, rb, rb);
        const float rua = ra * ua;
        const float rub = rb * ub;

        a_r  = __builtin_fmaf(ra,  A0.w, a_r);
        a_r  = __builtin_fmaf(rb,  B0.w, a_r);
        a_u1 = __builtin_fmaf(ua,  A1.x, a_u1);
        a_u1 = __builtin_fmaf(ub,  B1.x, a_u1);
        a_u2 = __builtin_fmaf(ua,  A1.y, a_u2);
        a_u2 = __builtin_fmaf(ub,  B1.y, a_u2);
        a_u3 = __builtin_fmaf(ua,  A1.z, a_u3);
        a_u3 = __builtin_fmaf(ub,  B1.z, a_u3);
        a_u4 = __builtin_fmaf(rua, A1.w, a_u4);
        a_u4 = __builtin_fmaf(rub, B1.w, a_u4);
    }

    const float aD = a_u3 + a_u4;

    __shared__ float4 red[WPB][64];
    if (wv != 0) {
        red[wv][lane] = make_float4(a_r, a_u1, a_u2, aD);
    }
    __syncthreads();
    if (wv == 0) {
        float s_r = a_r, s_u1 = a_u1, s_u2 = a_u2, sD = aD;
        #pragma unroll
        for (int w = 1; w < WPB; ++w) {
            const float4 o = red[w][lane];
            s_r += o.x; s_u1 += o.y; s_u2 += o.z; sD += o.w;
        }
        const float f    = sw2p[0] + b2p[0] + s_r;   // sum t*w2 + b2
        const float ft   = s_u1;                     // df_dt
        const float fx   = s_u2;                     // df_dx
        const float fxx  = -2.0f * sD;               // df_dxdx
        gridout[idx] = make_float4(f, ft, fx, fxx);
    }
}

// Catmull-Rom weights for t in [0,1)
static __device__ __forceinline__ void cr_w(float t, float w[4]) {
    w[0] = t * (-0.5f + t * (1.0f - 0.5f * t));
    w[1] = 1.0f + t * t * (-2.5f + 1.5f * t);
    w[2] = t * (0.5f + t * (2.0f - 1.5f * t));
    w[3] = t * t * (-0.5f + 0.5f * t);
}

__global__ __launch_bounds__(256) void interp_kernel(const float2* __restrict__ x2,
                                                     const unsigned* __restrict__ bnd,
                                                     const float4* __restrict__ grid,
                                                     float* __restrict__ out) {
    const int i = blockIdx.x * 256 + threadIdx.x;
    const float2 xv = x2[i];
    const float4 mp = grid_map(bnd);
    const float inv0 = __builtin_amdgcn_rcpf(mp.y);
    const float inv1 = __builtin_amdgcn_rcpf(mp.w);

    float u = (xv.x - mp.x) * inv0;
    float v = (xv.y - mp.z) * inv1;
    u = fminf(fmaxf(u, 0.0f), (float)(G - 1) - 1e-3f);
    v = fminf(fmaxf(v, 0.0f), (float)(G - 1) - 1e-3f);
    int iu = (int)u;  iu = iu > G - 2 ? G - 2 : iu;
    int iv = (int)v;  iv = iv > G - 2 ? G - 2 : iv;
    const float fu = u - (float)iu;
    const float fv = v - (float)iv;

    float wu[4], wv_[4];
    cr_w(fu, wu);
    cr_w(fv, wv_);

    const int ju0 = iu - 1 < 0 ? 0 : iu - 1;
    const int ju1 = iu;
    const int ju2 = iu + 1;
    const int ju3 = iu + 2 > G - 1 ? G - 1 : iu + 2;
    const int jv0 = iv - 1 < 0 ? 0 : iv - 1;
    const int jv3 = iv + 2 > G - 1 ? G - 1 : iv + 2;
    const int rows[4] = { jv0 * G, iv * G, (iv + 1) * G, jv3 * G };

    float af = 0.f, at = 0.f, ax = 0.f, axx = 0.f;
    #pragma unroll
    for (int r = 0; r < 4; ++r) {
        const int base = rows[r];
        const float4 g0 = grid[base + ju0];
        const float4 g1 = grid[base + ju1];
        const float4 g2 = grid[base + ju2];
        const float4 g3 = grid[base + ju3];
        const float rf  = wu[0] * g0.x + wu[1] * g1.x + wu[2] * g2.x + wu[3] * g3.x;
        const float rt  = wu[0] * g0.y + wu[1] * g1.y + wu[2] * g2.y + wu[3] * g3.y;
        const float rx  = wu[0] * g0.z + wu[1] * g1.z + wu[2] * g2.z + wu[3] * g3.z;
        const float rxx = wu[0] * g0.w + wu[1] * g1.w + wu[2] * g2.w + wu[3] * g3.w;
        af  = __builtin_fmaf(wv_[r], rf,  af);
        at  = __builtin_fmaf(wv_[r], rt,  at);
        ax  = __builtin_fmaf(wv_[r], rx,  ax);
        axx = __builtin_fmaf(wv_[r], rxx, axx);
    }

    const float x1 = xv.y;
    const float pde = __builtin_fmaf(0.5f * x1, x1, at)
                    + 0.5f * axx
                    + 0.5f * x1 * ax
                    - 0.069444444444444445f * ax * ax;
    out[i] = af;
    out[PN + i] = pde;
}

extern "C" void kernel_launch(void* const* d_in, const int* in_sizes, int n_in,
                              void* d_out, int out_size, void* d_ws, size_t ws_size,
                              hipStream_t stream) {
    const float* x  = (const float*)d_in[0];
    const float* W1 = (const float*)d_in[1];
    const float* b1 = (const float*)d_in[2];
    const float* w2 = (const float*)d_in[3];
    const float* b2 = (const float*)d_in[4];
    float* out = (float*)d_out;

    float* pk      = (float*)d_ws;                    // 8192 floats
    float* sw2     = pk + 8192;
    unsigned* bnd  = (unsigned*)(pk + 8200);          // 4 uints
    uint4* part    = (uint4*)(pk + 8208);             // NB1 uint4
    float4* grid   = (float4*)(pk + 8960);            // G*G float4 = 256 KiB

    const float2* x2 = (const float2*)x;

    prep_kernel<<<1, 256, 0, stream>>>(W1, b1, w2, pk, sw2);
    bounds1_kernel<<<NB1, 256, 0, stream>>>((const float4*)x, part);
    bounds2_kernel<<<1, 64, 0, stream>>>(part, bnd);
    grid_eval_kernel<<<GPTS / 64, 512, 0, stream>>>((const float4*)pk, sw2, b2, bnd, grid);
    interp_kernel<<<PN / 256, 256, 0, stream>>>(x2, bnd, grid, out);
}